// Round 10
// baseline (251.608 us; speedup 1.0000x reference)
//
#include <hip/hip_runtime.h>
#include <stdint.h>

typedef __attribute__((ext_vector_type(8))) short short8;
typedef __attribute__((ext_vector_type(4))) float f32x4;
typedef __attribute__((ext_vector_type(4))) unsigned int u32x4;
typedef __attribute__((ext_vector_type(2))) unsigned int u32x2;

#define MFMA16(a, b, c) __builtin_amdgcn_mfma_f32_16x16x32_bf16((a), (b), (c), 0, 0, 0)

// async global->LDS DMA, 16B per lane; LDS dest = wave-uniform base + lane*16
#define GLD_LDS16(g, l)                                                                  \
    __builtin_amdgcn_global_load_lds((const __attribute__((address_space(1))) void*)(g), \
                                     (__attribute__((address_space(3))) void*)(l), 16, 0, 0)

// single-instruction v_exp_f32 (exp2f without -ffast-math is a slow libm call)
#if defined(__has_builtin)
#if __has_builtin(__builtin_amdgcn_exp2f)
#define FAST_EXP2(x) __builtin_amdgcn_exp2f(x)
#endif
#endif
#ifndef FAST_EXP2
__device__ __forceinline__ float fast_exp2_asm(float x) {
    float r;
    asm volatile("v_exp_f32 %0, %1\ns_nop 1" : "=v"(r) : "v"(x));
    return r;
}
#define FAST_EXP2(x) fast_exp2_asm(x)
#endif

__device__ __forceinline__ float bf2f(unsigned short u) {
    unsigned int x = ((unsigned int)u) << 16;
    float f;
    __builtin_memcpy(&f, &x, 4);
    return f;
}
__device__ __forceinline__ unsigned short f2bf(float f) {  // RNE
    unsigned int x;
    __builtin_memcpy(&x, &f, 4);
    unsigned int r = x + 0x7FFFu + ((x >> 16) & 1u);
    return (unsigned short)(r >> 16);
}
// pack two f32 -> two bf16 (round-half-up) in one u32
__device__ __forceinline__ unsigned int pack2bf(float a, float b) {
    unsigned int ua, ub;
    __builtin_memcpy(&ua, &a, 4);
    __builtin_memcpy(&ub, &b, 4);
    return __builtin_amdgcn_perm(ub + 0x8000u, ua + 0x8000u, 0x07060302u);
}
__device__ __forceinline__ u32x4 cvt8(const float* p) {
    f32x4 g0 = *(const f32x4*)p;
    f32x4 g1 = *(const f32x4*)(p + 4);
    u32x4 r;
    r.x = pack2bf(g0[0], g0[1]);
    r.y = pack2bf(g0[2], g0[3]);
    r.z = pack2bf(g1[0], g1[1]);
    r.w = pack2bf(g1[2], g1[3]);
    return r;
}

// elementwise f32 -> bf16 (x8 per thread)
__global__ __launch_bounds__(256) void cvt_kernel(const float* __restrict__ in,
                                                  unsigned short* __restrict__ out, int n8) {
    int i = blockIdx.x * 256 + threadIdx.x;
    if (i < n8) *(u32x4*)(out + (size_t)i * 8) = cvt8(in + (size_t)i * 8);
}

// ---------- main-path GEMM (r7 config: BM=BN=128, BK=64, global_load_lds) ----------
// C = A @ B^T + bias; A [M,K] bf16, B [N,K] bf16 (weight [out,in]).
// MODE 0: C bf16 scattered head-major V [bh=bb*16+h][n][dh]; MODE 1: C f32 row-major.
template <int MODE>
__global__ __launch_bounds__(256) void gemm_dma_kernel(
    const unsigned short* __restrict__ A, const unsigned short* __restrict__ B,
    const float* __restrict__ bias, void* __restrict__ Cv, int M, int N, int K) {
    __shared__ __align__(16) unsigned short As0[128 * 32];
    __shared__ __align__(16) unsigned short As1[128 * 32];
    __shared__ __align__(16) unsigned short Bs0[128 * 32];
    __shared__ __align__(16) unsigned short Bs1[128 * 32];

    const int tid = threadIdx.x;
    const int wave = tid >> 6, lane = tid & 63;
    const int l15 = lane & 15, quad = lane >> 4;
    const int m0 = blockIdx.x * 128, n0 = blockIdx.y * 128;
    const int wm = (wave >> 1) * 64, wn = (wave & 1) * 64;

    const int row0 = tid >> 2, c0 = (tid & 3) * 8;
    const unsigned short* Ag0 = A + (size_t)(m0 + row0) * K + c0;
    const unsigned short* Ag1 = A + (size_t)(m0 + row0 + 64) * K + c0;
    const unsigned short* Bg0 = B + (size_t)(n0 + row0) * K + c0;
    const unsigned short* Bg1 = B + (size_t)(n0 + row0 + 64) * K + c0;
    unsigned short* lA0a = As0 + wave * 512;
    unsigned short* lA0b = As0 + 2048 + wave * 512;
    unsigned short* lA1a = As1 + wave * 512;
    unsigned short* lA1b = As1 + 2048 + wave * 512;
    unsigned short* lB0a = Bs0 + wave * 512;
    unsigned short* lB0b = Bs0 + 2048 + wave * 512;
    unsigned short* lB1a = Bs1 + wave * 512;
    unsigned short* lB1b = Bs1 + 2048 + wave * 512;

    f32x4 acc[4][4];
#pragma unroll
    for (int i = 0; i < 4; i++)
#pragma unroll
        for (int j = 0; j < 4; j++) {
            f32x4 z = {0.f, 0.f, 0.f, 0.f};
            acc[i][j] = z;
        }

    for (int k0 = 0; k0 < K; k0 += 64) {
        __syncthreads();
        GLD_LDS16(Ag0 + k0, lA0a);
        GLD_LDS16(Ag1 + k0, lA0b);
        GLD_LDS16(Ag0 + k0 + 32, lA1a);
        GLD_LDS16(Ag1 + k0 + 32, lA1b);
        GLD_LDS16(Bg0 + k0, lB0a);
        GLD_LDS16(Bg1 + k0, lB0b);
        GLD_LDS16(Bg0 + k0 + 32, lB1a);
        GLD_LDS16(Bg1 + k0 + 32, lB1b);
        __syncthreads();

        short8 a0[4], a1[4], b0[4], b1[4];
#pragma unroll
        for (int mt = 0; mt < 4; mt++) {
            a0[mt] = *(const short8*)&As0[(wm + mt * 16 + l15) * 32 + quad * 8];
            a1[mt] = *(const short8*)&As1[(wm + mt * 16 + l15) * 32 + quad * 8];
        }
#pragma unroll
        for (int nt = 0; nt < 4; nt++) {
            b0[nt] = *(const short8*)&Bs0[(wn + nt * 16 + l15) * 32 + quad * 8];
            b1[nt] = *(const short8*)&Bs1[(wn + nt * 16 + l15) * 32 + quad * 8];
        }
#pragma unroll
        for (int mt = 0; mt < 4; mt++)
#pragma unroll
            for (int nt = 0; nt < 4; nt++) acc[mt][nt] = MFMA16(a0[mt], b0[nt], acc[mt][nt]);
#pragma unroll
        for (int mt = 0; mt < 4; mt++)
#pragma unroll
            for (int nt = 0; nt < 4; nt++) acc[mt][nt] = MFMA16(a1[mt], b1[nt], acc[mt][nt]);
    }

    float bv[4];
#pragma unroll
    for (int nt = 0; nt < 4; nt++) bv[nt] = bias[n0 + wn + nt * 16 + l15];

#pragma unroll
    for (int mt = 0; mt < 4; mt++)
#pragma unroll
        for (int nt = 0; nt < 4; nt++)
#pragma unroll
            for (int i = 0; i < 4; i++) {
                int m = m0 + wm + mt * 16 + quad * 4 + i;
                int n = n0 + wn + nt * 16 + l15;
                float val = acc[mt][nt][i] + bv[nt];
                if (MODE == 0) {
                    int bb = m >> 11, ns = m & 2047, h = n >> 6, c = n & 63;
                    ((unsigned short*)Cv)[(size_t)(bb * 16 + h) * 131072 + (size_t)ns * 64 + c] =
                        f2bf(val);
                } else {
                    ((float*)Cv)[(size_t)m * N + n] = val;
                }
            }
}

// ---------- fallback GEMM (f32 operands, inline convert, LDS-staged) ----------
template <bool AF32, bool BF32, int MODE>
__global__ __launch_bounds__(256) void gemm_bias_kernel(
    const void* __restrict__ Av, const void* __restrict__ Bv,
    const float* __restrict__ bias, void* __restrict__ Cv, int M, int N, int K) {
    __shared__ __align__(16) unsigned short As[128][40];
    __shared__ __align__(16) unsigned short Bs[128][40];

    const int tid = threadIdx.x;
    const int wave = tid >> 6, lane = tid & 63;
    const int l15 = lane & 15, quad = lane >> 4;
    const int m0 = blockIdx.x * 128, n0 = blockIdx.y * 128;
    const int wm = (wave >> 1) * 64, wn = (wave & 1) * 64;

    f32x4 acc[4][4];
#pragma unroll
    for (int i = 0; i < 4; i++)
#pragma unroll
        for (int j = 0; j < 4; j++) {
            f32x4 z = {0.f, 0.f, 0.f, 0.f};
            acc[i][j] = z;
        }

    for (int k0 = 0; k0 < K; k0 += 32) {
        __syncthreads();
#pragma unroll
        for (int rep = 0; rep < 2; rep++) {
            int chunk = tid + rep * 256;
            int row = chunk >> 2, c8 = (chunk & 3) * 8;
            if (AF32) {
                const float* Af = (const float*)Av;
                *(u32x4*)&As[row][c8] = cvt8(&Af[(size_t)(m0 + row) * K + k0 + c8]);
            } else {
                const unsigned short* Ab = (const unsigned short*)Av;
                *(f32x4*)&As[row][c8] = *(const f32x4*)&Ab[(size_t)(m0 + row) * K + k0 + c8];
            }
            if (BF32) {
                const float* Bf = (const float*)Bv;
                *(u32x4*)&Bs[row][c8] = cvt8(&Bf[(size_t)(n0 + row) * K + k0 + c8]);
            } else {
                const unsigned short* Bb = (const unsigned short*)Bv;
                *(f32x4*)&Bs[row][c8] = *(const f32x4*)&Bb[(size_t)(n0 + row) * K + k0 + c8];
            }
        }
        __syncthreads();

        short8 a[4], b[4];
#pragma unroll
        for (int mt = 0; mt < 4; mt++) a[mt] = *(const short8*)&As[wm + mt * 16 + l15][quad * 8];
#pragma unroll
        for (int nt = 0; nt < 4; nt++) b[nt] = *(const short8*)&Bs[wn + nt * 16 + l15][quad * 8];
#pragma unroll
        for (int mt = 0; mt < 4; mt++)
#pragma unroll
            for (int nt = 0; nt < 4; nt++) acc[mt][nt] = MFMA16(a[mt], b[nt], acc[mt][nt]);
    }

    float bv[4];
#pragma unroll
    for (int nt = 0; nt < 4; nt++) bv[nt] = bias[n0 + wn + nt * 16 + l15];

#pragma unroll
    for (int mt = 0; mt < 4; mt++)
#pragma unroll
        for (int nt = 0; nt < 4; nt++)
#pragma unroll
            for (int i = 0; i < 4; i++) {
                int m = m0 + wm + mt * 16 + quad * 4 + i;
                int n = n0 + wn + nt * 16 + l15;
                float val = acc[mt][nt][i] + bv[nt];
                if (MODE == 0) {
                    int bb = m >> 11, ns = m & 2047, h = n >> 6, c = n & 63;
                    ((unsigned short*)Cv)[(size_t)(bb * 16 + h) * 131072 + (size_t)ns * 64 + c] =
                        f2bf(val);
                } else {
                    ((float*)Cv)[(size_t)m * N + n] = val;
                }
            }
}

// V [bh][2048][64] bf16 -> Vt [bh][64][2048] bf16.  64x64 tiles via LDS.
__global__ __launch_bounds__(256) void transpose_kernel(const unsigned short* __restrict__ V,
                                                        unsigned short* __restrict__ Vt) {
    __shared__ __align__(16) unsigned short T[64][72];
    const int tid = threadIdx.x;
    const int n0 = blockIdx.x * 64;
    const size_t base = (size_t)blockIdx.y * 131072;
#pragma unroll
    for (int rep = 0; rep < 2; rep++) {
        int chunk = tid + rep * 256;
        int row = chunk >> 3, c8 = (chunk & 7) * 8;
        *(short8*)&T[row][c8] = *(const short8*)&V[base + (size_t)(n0 + row) * 64 + c8];
    }
    __syncthreads();
#pragma unroll
    for (int rep = 0; rep < 2; rep++) {
        int chunk = tid + rep * 256;
        int d = chunk >> 3, n8 = (chunk & 7) * 8;
        short8 o;
#pragma unroll
        for (int j = 0; j < 8; j++) o[j] = (short)T[n8 + j][d];
        *(short8*)&Vt[base + (size_t)d * 2048 + n0 + n8] = o;
    }
}

// Flash attention, q=k=v=V, fixed-max softmax, S^T=K.Q^T form, FAST_EXP2.
// r10 change: 64 q-rows PER WAVE (block = 128 threads, 2 waves) — halves the
// per-q duplication of K/V^T LDS fragment reads (attn was LDS-pipe-bound:
// 16 waves x 28 DS-instr/tile ~= 205k cy/CU ~= the measured 95 us).
__global__ __launch_bounds__(128, 2) void attn_kernel(const unsigned short* __restrict__ V,
                                                      const unsigned short* __restrict__ Vt,
                                                      unsigned short* __restrict__ O) {
    __shared__ __align__(16) unsigned short QP[128 * 72];  // Q, then P rows (wave-private)
    __shared__ __align__(16) unsigned short Ks0[64 * 32];  // kv rows, dh cols 0-31
    __shared__ __align__(16) unsigned short Ks1[64 * 32];  // dh cols 32-63
    __shared__ __align__(16) unsigned short VT0[64 * 32];  // dh rows, kv cols 0-31
    __shared__ __align__(16) unsigned short VT1[64 * 32];  // kv cols 32-63

    const int tid = threadIdx.x;
    const int wave = tid >> 6, lane = tid & 63;
    const int l15 = lane & 15, quad = lane >> 4;
    const int q0 = blockIdx.x * 128, bh = blockIdx.y;
    const unsigned short* Vh = V + (size_t)bh * 131072;
    const unsigned short* VhT = Vt + (size_t)bh * 131072;
    const int wm = wave * 64;  // 64 q-rows per wave

    // stage Q tile; scale = 0.125 * log2(e) folded
#pragma unroll
    for (int rep = 0; rep < 8; rep++) {
        int chunk = tid + rep * 128;
        int row = chunk >> 3, c8 = (chunk & 7) * 8;
        short8 g = *(const short8*)&Vh[(size_t)(q0 + row) * 64 + c8];
        short8 o;
#pragma unroll
        for (int j = 0; j < 8; j++)
            o[j] = (short)f2bf(bf2f((unsigned short)g[j]) * 0.1803368801f);
        *(short8*)&QP[row * 72 + c8] = o;
    }
    __syncthreads();

    // Q B-fragments (loop-invariant); QP rows become wave-private P space
    short8 bq[4][2];
#pragma unroll
    for (int mt = 0; mt < 4; mt++)
#pragma unroll
        for (int ks = 0; ks < 2; ks++)
            bq[mt][ks] = *(const short8*)&QP[(wm + mt * 16 + l15) * 72 + ks * 32 + quad * 8];

    const int rl = lane >> 2;        // 0..15
    const int cl4 = (lane & 3) * 8;  // 0/8/16/24

    f32x4 oacc[4][4];
#pragma unroll
    for (int mt = 0; mt < 4; mt++)
#pragma unroll
        for (int ct = 0; ct < 4; ct++) {
            f32x4 z = {0.f, 0.f, 0.f, 0.f};
            oacc[mt][ct] = z;
        }
    float lsum[4] = {0.f, 0.f, 0.f, 0.f};

    for (int kv0 = 0; kv0 < 2048; kv0 += 64) {
        __syncthreads();  // prev tile frag reads done before DMA overwrites
#pragma unroll
        for (int i = 0; i < 2; i++) {
            const int rb = i * 32 + wave * 16;  // wave-uniform row base
            GLD_LDS16(Vh + (size_t)(kv0 + rb + rl) * 64 + cl4, Ks0 + rb * 32);
            GLD_LDS16(Vh + (size_t)(kv0 + rb + rl) * 64 + 32 + cl4, Ks1 + rb * 32);
            GLD_LDS16(VhT + (size_t)(rb + rl) * 2048 + kv0 + cl4, VT0 + rb * 32);
            GLD_LDS16(VhT + (size_t)(rb + rl) * 2048 + kv0 + 32 + cl4, VT1 + rb * 32);
        }
        __syncthreads();  // vmcnt drained at barrier -> DMA complete

        // S^T tiles: C[row=kv local, col=q local]; A=K-frag, B=Q-frag
        f32x4 st[4][4];
#pragma unroll
        for (int nt = 0; nt < 4; nt++) {
            short8 ak0 = *(const short8*)&Ks0[(nt * 16 + l15) * 32 + quad * 8];
            short8 ak1 = *(const short8*)&Ks1[(nt * 16 + l15) * 32 + quad * 8];
#pragma unroll
            for (int mt = 0; mt < 4; mt++) {
                f32x4 z = {0.f, 0.f, 0.f, 0.f};
                z = MFMA16(ak0, bq[mt][0], z);
                z = MFMA16(ak1, bq[mt][1], z);
                st[nt][mt] = z;
            }
        }

        // fixed-max softmax: P = 2^s; packed b64 P-writes into own q-rows
#pragma unroll
        for (int mt = 0; mt < 4; mt++) {
            const int prow = (wm + mt * 16 + l15) * 72;
#pragma unroll
            for (int nt = 0; nt < 4; nt++) {
                f32x4 p;
#pragma unroll
                for (int i = 0; i < 4; i++) p[i] = FAST_EXP2(st[nt][mt][i]);
                lsum[mt] += (p[0] + p[1]) + (p[2] + p[3]);
                u32x2 w;
                w.x = pack2bf(p[0], p[1]);
                w.y = pack2bf(p[2], p[3]);
                *(u32x2*)&QP[prow + nt * 16 + quad * 4] = w;
            }
        }
        // P rows are wave-private: wave-local LDS drain suffices
        asm volatile("s_waitcnt lgkmcnt(0)" ::: "memory");

        // O += P . V
#pragma unroll
        for (int kt = 0; kt < 2; kt++) {
            const unsigned short* VTk = kt ? VT1 : VT0;
            short8 ap[4];
#pragma unroll
            for (int mt = 0; mt < 4; mt++)
                ap[mt] = *(const short8*)&QP[(wm + mt * 16 + l15) * 72 + kt * 32 + quad * 8];
#pragma unroll
            for (int ct = 0; ct < 4; ct++) {
                short8 bvf = *(const short8*)&VTk[(ct * 16 + l15) * 32 + quad * 8];
#pragma unroll
                for (int mt = 0; mt < 4; mt++) oacc[mt][ct] = MFMA16(ap[mt], bvf, oacc[mt][ct]);
            }
        }
    }

    // reduce lsum across quads, broadcast 1/sum to C-layout rows
    float inv[4][4];
#pragma unroll
    for (int mt = 0; mt < 4; mt++) {
        float v = lsum[mt];
        v += __shfl_xor(v, 16, 64);
        v += __shfl_xor(v, 32, 64);
        float r = 1.0f / v;  // lane l15 holds 1/rowsum(q = wm+mt*16+l15)
#pragma unroll
        for (int i = 0; i < 4; i++) inv[mt][i] = __shfl(r, quad * 4 + i, 16);
    }

    const int bb = bh >> 4, h = bh & 15;
#pragma unroll
    for (int mt = 0; mt < 4; mt++)
#pragma unroll
        for (int i = 0; i < 4; i++) {
            int m = q0 + wm + mt * 16 + quad * 4 + i;
            size_t rowbase = ((size_t)(bb * 2048 + m)) * 1024 + h * 64;
#pragma unroll
            for (int ct = 0; ct < 4; ct++)
                O[rowbase + ct * 16 + l15] = f2bf(oacc[mt][ct][i] * inv[mt][i]);
        }
}

extern "C" void kernel_launch(void* const* d_in, const int* in_sizes, int n_in, void* d_out,
                              int out_size, void* d_ws, size_t ws_size, hipStream_t stream) {
    (void)in_sizes; (void)n_in; (void)out_size;
    const float* x = (const float*)d_in[0];    // [4,2048,1024] f32
    const float* v_w = (const float*)d_in[1];  // [1024,1024] (out,in)
    const float* v_b = (const float*)d_in[2];  // [1024]
    const float* o_w = (const float*)d_in[3];  // [1024,1024]
    const float* o_b = (const float*)d_in[4];  // [1024]
    float* out = (float*)d_out;                // [8192,1024] f32 = 32 MB

    unsigned short* Vbuf = (unsigned short*)d_out;       // V bf16 (16 MB)
    unsigned short* Vtbuf = Vbuf + (size_t)8192 * 1024;  // Vt bf16 (16 MB)
    unsigned short* Obuf = (unsigned short*)d_ws;        // 16.78 MB (proven OK)

    const size_t need =
        ((size_t)8192 * 1024 /*Obuf*/ + (size_t)8192 * 1024 /*x*/ + 2 * (size_t)1024 * 1024) * 2;
    if (ws_size >= need) {
        unsigned short* xbf = Obuf + (size_t)8192 * 1024;
        unsigned short* wv = xbf + (size_t)8192 * 1024;
        unsigned short* wo = wv + (size_t)1024 * 1024;
        cvt_kernel<<<4096, 256, 0, stream>>>(x, xbf, 1048576);
        cvt_kernel<<<512, 256, 0, stream>>>(v_w, wv, 131072);
        cvt_kernel<<<512, 256, 0, stream>>>(o_w, wo, 131072);
        gemm_dma_kernel<0><<<dim3(64, 8), 256, 0, stream>>>(xbf, wv, v_b, Vbuf, 8192, 1024, 1024);
        transpose_kernel<<<dim3(32, 64), 256, 0, stream>>>(Vbuf, Vtbuf);
        attn_kernel<<<dim3(16, 64), 128, 0, stream>>>(Vbuf, Vtbuf, Obuf);
        gemm_dma_kernel<1><<<dim3(64, 8), 256, 0, stream>>>(Obuf, wo, o_b, out, 8192, 1024, 1024);
    } else {
        gemm_bias_kernel<true, true, 0>
            <<<dim3(64, 8), 256, 0, stream>>>(x, v_w, v_b, Vbuf, 8192, 1024, 1024);
        transpose_kernel<<<dim3(32, 64), 256, 0, stream>>>(Vbuf, Vtbuf);
        attn_kernel<<<dim3(16, 64), 128, 0, stream>>>(Vbuf, Vtbuf, Obuf);
        gemm_bias_kernel<false, true, 1>
            <<<dim3(64, 8), 256, 0, stream>>>(Obuf, o_w, o_b, out, 8192, 1024, 1024);
    }
}

// Round 11
// 230.900 us; speedup vs baseline: 1.0897x; 1.0897x over previous
//
#include <hip/hip_runtime.h>
#include <stdint.h>

typedef __attribute__((ext_vector_type(8))) short short8;
typedef __attribute__((ext_vector_type(4))) float f32x4;
typedef __attribute__((ext_vector_type(4))) unsigned int u32x4;
typedef __attribute__((ext_vector_type(2))) unsigned int u32x2;

#define MFMA16(a, b, c) __builtin_amdgcn_mfma_f32_16x16x32_bf16((a), (b), (c), 0, 0, 0)

// async global->LDS DMA, 16B per lane; LDS dest = wave-uniform base + lane*16
#define GLD_LDS16(g, l)                                                                  \
    __builtin_amdgcn_global_load_lds((const __attribute__((address_space(1))) void*)(g), \
                                     (__attribute__((address_space(3))) void*)(l), 16, 0, 0)

// single-instruction v_exp_f32 (exp2f without -ffast-math is a slow libm call)
#if defined(__has_builtin)
#if __has_builtin(__builtin_amdgcn_exp2f)
#define FAST_EXP2(x) __builtin_amdgcn_exp2f(x)
#endif
#endif
#ifndef FAST_EXP2
__device__ __forceinline__ float fast_exp2_asm(float x) {
    float r;
    asm volatile("v_exp_f32 %0, %1\ns_nop 1" : "=v"(r) : "v"(x));
    return r;
}
#define FAST_EXP2(x) fast_exp2_asm(x)
#endif

__device__ __forceinline__ float bf2f(unsigned short u) {
    unsigned int x = ((unsigned int)u) << 16;
    float f;
    __builtin_memcpy(&f, &x, 4);
    return f;
}
__device__ __forceinline__ unsigned short f2bf(float f) {  // RNE
    unsigned int x;
    __builtin_memcpy(&x, &f, 4);
    unsigned int r = x + 0x7FFFu + ((x >> 16) & 1u);
    return (unsigned short)(r >> 16);
}
// pack two f32 -> two bf16 (round-half-up) in one u32
__device__ __forceinline__ unsigned int pack2bf(float a, float b) {
    unsigned int ua, ub;
    __builtin_memcpy(&ua, &a, 4);
    __builtin_memcpy(&ub, &b, 4);
    return __builtin_amdgcn_perm(ub + 0x8000u, ua + 0x8000u, 0x07060302u);
}
__device__ __forceinline__ u32x4 cvt8(const float* p) {
    f32x4 g0 = *(const f32x4*)p;
    f32x4 g1 = *(const f32x4*)(p + 4);
    u32x4 r;
    r.x = pack2bf(g0[0], g0[1]);
    r.y = pack2bf(g0[2], g0[3]);
    r.z = pack2bf(g1[0], g1[1]);
    r.w = pack2bf(g1[2], g1[3]);
    return r;
}

// elementwise f32 -> bf16 (x8 per thread)
__global__ __launch_bounds__(256) void cvt_kernel(const float* __restrict__ in,
                                                  unsigned short* __restrict__ out, int n8) {
    int i = blockIdx.x * 256 + threadIdx.x;
    if (i < n8) *(u32x4*)(out + (size_t)i * 8) = cvt8(in + (size_t)i * 8);
}

// ---------- main-path GEMM: BM=BN=128, BK=64, DOUBLE-BUFFERED global_load_lds ----------
// Grid caps occupancy at 2 blocks/CU, so 64 KB LDS is free. One barrier per K-iter:
// the barrier drains a DMA issued one full compute phase earlier (latency covered),
// then the next stage's DMA is issued into the other buffer before the frag reads.
// C = A @ B^T + bias; A [M,K] bf16, B [N,K] bf16 (weight [out,in]).
// MODE 0: C bf16 scattered head-major V [bh=bb*16+h][n][dh]; MODE 1: C f32 row-major.
template <int MODE>
__global__ __launch_bounds__(256) void gemm_dma_kernel(
    const unsigned short* __restrict__ A, const unsigned short* __restrict__ B,
    const float* __restrict__ bias, void* __restrict__ Cv, int M, int N, int K) {
    __shared__ __align__(16) unsigned short As[2][2][128 * 32];  // [stage][k-half]
    __shared__ __align__(16) unsigned short Bs[2][2][128 * 32];

    const int tid = threadIdx.x;
    const int wave = tid >> 6, lane = tid & 63;
    const int l15 = lane & 15, quad = lane >> 4;
    const int m0 = blockIdx.x * 128, n0 = blockIdx.y * 128;
    const int wm = (wave >> 1) * 64, wn = (wave & 1) * 64;

    const int row0 = tid >> 2, c0 = (tid & 3) * 8;
    const unsigned short* Ag0 = A + (size_t)(m0 + row0) * K + c0;       // rows 0-63
    const unsigned short* Ag1 = A + (size_t)(m0 + row0 + 64) * K + c0;  // rows 64-127
    const unsigned short* Bg0 = B + (size_t)(n0 + row0) * K + c0;
    const unsigned short* Bg1 = B + (size_t)(n0 + row0 + 64) * K + c0;
    const int wl = wave * 512;  // wave-uniform LDS offset (lane*16B appended by HW)

#define STAGE(s, k0)                                     \
    do {                                                 \
        GLD_LDS16(Ag0 + (k0), &As[s][0][wl]);            \
        GLD_LDS16(Ag1 + (k0), &As[s][0][2048 + wl]);     \
        GLD_LDS16(Ag0 + (k0) + 32, &As[s][1][wl]);       \
        GLD_LDS16(Ag1 + (k0) + 32, &As[s][1][2048 + wl]); \
        GLD_LDS16(Bg0 + (k0), &Bs[s][0][wl]);            \
        GLD_LDS16(Bg1 + (k0), &Bs[s][0][2048 + wl]);     \
        GLD_LDS16(Bg0 + (k0) + 32, &Bs[s][1][wl]);       \
        GLD_LDS16(Bg1 + (k0) + 32, &Bs[s][1][2048 + wl]); \
    } while (0)

    f32x4 acc[4][4];
#pragma unroll
    for (int i = 0; i < 4; i++)
#pragma unroll
        for (int j = 0; j < 4; j++) {
            f32x4 z = {0.f, 0.f, 0.f, 0.f};
            acc[i][j] = z;
        }

    STAGE(0, 0);  // prologue
    for (int k0 = 0; k0 < K; k0 += 64) {
        const int s = (k0 >> 6) & 1;
        // Drains the DMA for stage s (issued one full iteration ago -> latency covered)
        // and separates prev iteration's reads of stage s^1 from the staging below.
        __syncthreads();
        if (k0 + 64 < K) STAGE(s ^ 1, k0 + 64);

        short8 a0[4], a1[4], b0[4], b1[4];
#pragma unroll
        for (int mt = 0; mt < 4; mt++) {
            a0[mt] = *(const short8*)&As[s][0][(wm + mt * 16 + l15) * 32 + quad * 8];
            a1[mt] = *(const short8*)&As[s][1][(wm + mt * 16 + l15) * 32 + quad * 8];
        }
#pragma unroll
        for (int nt = 0; nt < 4; nt++) {
            b0[nt] = *(const short8*)&Bs[s][0][(wn + nt * 16 + l15) * 32 + quad * 8];
            b1[nt] = *(const short8*)&Bs[s][1][(wn + nt * 16 + l15) * 32 + quad * 8];
        }
#pragma unroll
        for (int mt = 0; mt < 4; mt++)
#pragma unroll
            for (int nt = 0; nt < 4; nt++) acc[mt][nt] = MFMA16(a0[mt], b0[nt], acc[mt][nt]);
#pragma unroll
        for (int mt = 0; mt < 4; mt++)
#pragma unroll
            for (int nt = 0; nt < 4; nt++) acc[mt][nt] = MFMA16(a1[mt], b1[nt], acc[mt][nt]);
    }
#undef STAGE

    float bv[4];
#pragma unroll
    for (int nt = 0; nt < 4; nt++) bv[nt] = bias[n0 + wn + nt * 16 + l15];

#pragma unroll
    for (int mt = 0; mt < 4; mt++)
#pragma unroll
        for (int nt = 0; nt < 4; nt++)
#pragma unroll
            for (int i = 0; i < 4; i++) {
                int m = m0 + wm + mt * 16 + quad * 4 + i;
                int n = n0 + wn + nt * 16 + l15;
                float val = acc[mt][nt][i] + bv[nt];
                if (MODE == 0) {
                    int bb = m >> 11, ns = m & 2047, h = n >> 6, c = n & 63;
                    ((unsigned short*)Cv)[(size_t)(bb * 16 + h) * 131072 + (size_t)ns * 64 + c] =
                        f2bf(val);
                } else {
                    ((float*)Cv)[(size_t)m * N + n] = val;
                }
            }
}

// ---------- fallback GEMM (f32 operands, inline convert, LDS-staged) ----------
template <bool AF32, bool BF32, int MODE>
__global__ __launch_bounds__(256) void gemm_bias_kernel(
    const void* __restrict__ Av, const void* __restrict__ Bv,
    const float* __restrict__ bias, void* __restrict__ Cv, int M, int N, int K) {
    __shared__ __align__(16) unsigned short As[128][40];
    __shared__ __align__(16) unsigned short Bs[128][40];

    const int tid = threadIdx.x;
    const int wave = tid >> 6, lane = tid & 63;
    const int l15 = lane & 15, quad = lane >> 4;
    const int m0 = blockIdx.x * 128, n0 = blockIdx.y * 128;
    const int wm = (wave >> 1) * 64, wn = (wave & 1) * 64;

    f32x4 acc[4][4];
#pragma unroll
    for (int i = 0; i < 4; i++)
#pragma unroll
        for (int j = 0; j < 4; j++) {
            f32x4 z = {0.f, 0.f, 0.f, 0.f};
            acc[i][j] = z;
        }

    for (int k0 = 0; k0 < K; k0 += 32) {
        __syncthreads();
#pragma unroll
        for (int rep = 0; rep < 2; rep++) {
            int chunk = tid + rep * 256;
            int row = chunk >> 2, c8 = (chunk & 3) * 8;
            if (AF32) {
                const float* Af = (const float*)Av;
                *(u32x4*)&As[row][c8] = cvt8(&Af[(size_t)(m0 + row) * K + k0 + c8]);
            } else {
                const unsigned short* Ab = (const unsigned short*)Av;
                *(f32x4*)&As[row][c8] = *(const f32x4*)&Ab[(size_t)(m0 + row) * K + k0 + c8];
            }
            if (BF32) {
                const float* Bf = (const float*)Bv;
                *(u32x4*)&Bs[row][c8] = cvt8(&Bf[(size_t)(n0 + row) * K + k0 + c8]);
            } else {
                const unsigned short* Bb = (const unsigned short*)Bv;
                *(f32x4*)&Bs[row][c8] = *(const f32x4*)&Bb[(size_t)(n0 + row) * K + k0 + c8];
            }
        }
        __syncthreads();

        short8 a[4], b[4];
#pragma unroll
        for (int mt = 0; mt < 4; mt++) a[mt] = *(const short8*)&As[wm + mt * 16 + l15][quad * 8];
#pragma unroll
        for (int nt = 0; nt < 4; nt++) b[nt] = *(const short8*)&Bs[wn + nt * 16 + l15][quad * 8];
#pragma unroll
        for (int mt = 0; mt < 4; mt++)
#pragma unroll
            for (int nt = 0; nt < 4; nt++) acc[mt][nt] = MFMA16(a[mt], b[nt], acc[mt][nt]);
    }

    float bv[4];
#pragma unroll
    for (int nt = 0; nt < 4; nt++) bv[nt] = bias[n0 + wn + nt * 16 + l15];

#pragma unroll
    for (int mt = 0; mt < 4; mt++)
#pragma unroll
        for (int nt = 0; nt < 4; nt++)
#pragma unroll
            for (int i = 0; i < 4; i++) {
                int m = m0 + wm + mt * 16 + quad * 4 + i;
                int n = n0 + wn + nt * 16 + l15;
                float val = acc[mt][nt][i] + bv[nt];
                if (MODE == 0) {
                    int bb = m >> 11, ns = m & 2047, h = n >> 6, c = n & 63;
                    ((unsigned short*)Cv)[(size_t)(bb * 16 + h) * 131072 + (size_t)ns * 64 + c] =
                        f2bf(val);
                } else {
                    ((float*)Cv)[(size_t)m * N + n] = val;
                }
            }
}

// V [bh][2048][64] bf16 -> Vt [bh][64][2048] bf16.  64x64 tiles via LDS.
__global__ __launch_bounds__(256) void transpose_kernel(const unsigned short* __restrict__ V,
                                                        unsigned short* __restrict__ Vt) {
    __shared__ __align__(16) unsigned short T[64][72];
    const int tid = threadIdx.x;
    const int n0 = blockIdx.x * 64;
    const size_t base = (size_t)blockIdx.y * 131072;
#pragma unroll
    for (int rep = 0; rep < 2; rep++) {
        int chunk = tid + rep * 256;
        int row = chunk >> 3, c8 = (chunk & 7) * 8;
        *(short8*)&T[row][c8] = *(const short8*)&V[base + (size_t)(n0 + row) * 64 + c8];
    }
    __syncthreads();
#pragma unroll
    for (int rep = 0; rep < 2; rep++) {
        int chunk = tid + rep * 256;
        int d = chunk >> 3, n8 = (chunk & 7) * 8;
        short8 o;
#pragma unroll
        for (int j = 0; j < 8; j++) o[j] = (short)T[n8 + j][d];
        *(short8*)&Vt[base + (size_t)d * 2048 + n0 + n8] = o;
    }
}

// Flash attention — r9 configuration verbatim (the r10 64-q/wave variant regressed:
// halving waves/CU cost more in latency hiding than the DS reduction bought).
// q=k=v=V, fixed-max softmax, S^T=K.Q^T form, FAST_EXP2, K/V^T via global_load_lds.
__global__ __launch_bounds__(256, 4) void attn_kernel(const unsigned short* __restrict__ V,
                                                      const unsigned short* __restrict__ Vt,
                                                      unsigned short* __restrict__ O) {
    __shared__ __align__(16) unsigned short QP[128 * 72];  // Q, then P rows (wave-private)
    __shared__ __align__(16) unsigned short Ks0[64 * 32];  // kv rows, dh cols 0-31
    __shared__ __align__(16) unsigned short Ks1[64 * 32];  // dh cols 32-63
    __shared__ __align__(16) unsigned short VT0[64 * 32];  // dh rows, kv cols 0-31
    __shared__ __align__(16) unsigned short VT1[64 * 32];  // kv cols 32-63

    const int tid = threadIdx.x;
    const int wave = tid >> 6, lane = tid & 63;
    const int l15 = lane & 15, quad = lane >> 4;
    const int q0 = blockIdx.x * 128, bh = blockIdx.y;
    const unsigned short* Vh = V + (size_t)bh * 131072;
    const unsigned short* VhT = Vt + (size_t)bh * 131072;
    const int wm = wave * 32;

    // stage Q tile; scale = 0.125 * log2(e) folded
#pragma unroll
    for (int rep = 0; rep < 4; rep++) {
        int chunk = tid + rep * 256;
        int row = chunk >> 3, c8 = (chunk & 7) * 8;
        short8 g = *(const short8*)&Vh[(size_t)(q0 + row) * 64 + c8];
        short8 o;
#pragma unroll
        for (int j = 0; j < 8; j++)
            o[j] = (short)f2bf(bf2f((unsigned short)g[j]) * 0.1803368801f);
        *(short8*)&QP[row * 72 + c8] = o;
    }
    __syncthreads();

    short8 bq[2][2];
#pragma unroll
    for (int mt = 0; mt < 2; mt++)
#pragma unroll
        for (int ks = 0; ks < 2; ks++)
            bq[mt][ks] = *(const short8*)&QP[(wm + mt * 16 + l15) * 72 + ks * 32 + quad * 8];

    const int rl = wave * 16 + (lane >> 2);
    const int cl = (lane & 3) * 8;
    const unsigned short* gK = Vh + (size_t)rl * 64 + cl;
    const unsigned short* gVT = VhT + (size_t)rl * 2048 + cl;
    unsigned short* lK0 = Ks0 + wave * 512;
    unsigned short* lK1 = Ks1 + wave * 512;
    unsigned short* lV0 = VT0 + wave * 512;
    unsigned short* lV1 = VT1 + wave * 512;

    f32x4 oacc[2][4];
#pragma unroll
    for (int mt = 0; mt < 2; mt++)
#pragma unroll
        for (int ct = 0; ct < 4; ct++) {
            f32x4 z = {0.f, 0.f, 0.f, 0.f};
            oacc[mt][ct] = z;
        }
    float lsum[2] = {0.f, 0.f};

    for (int kv0 = 0; kv0 < 2048; kv0 += 64) {
        __syncthreads();
        GLD_LDS16(gK + (size_t)kv0 * 64, lK0);
        GLD_LDS16(gK + (size_t)kv0 * 64 + 32, lK1);
        GLD_LDS16(gVT + kv0, lV0);
        GLD_LDS16(gVT + kv0 + 32, lV1);
        __syncthreads();

        f32x4 st[4][2];
#pragma unroll
        for (int nt = 0; nt < 4; nt++) {
            short8 ak0 = *(const short8*)&Ks0[(nt * 16 + l15) * 32 + quad * 8];
            short8 ak1 = *(const short8*)&Ks1[(nt * 16 + l15) * 32 + quad * 8];
#pragma unroll
            for (int mt = 0; mt < 2; mt++) {
                f32x4 z = {0.f, 0.f, 0.f, 0.f};
                z = MFMA16(ak0, bq[mt][0], z);
                z = MFMA16(ak1, bq[mt][1], z);
                st[nt][mt] = z;
            }
        }

#pragma unroll
        for (int mt = 0; mt < 2; mt++) {
            const int prow = (wm + mt * 16 + l15) * 72;
#pragma unroll
            for (int nt = 0; nt < 4; nt++) {
                f32x4 p;
#pragma unroll
                for (int i = 0; i < 4; i++) p[i] = FAST_EXP2(st[nt][mt][i]);
                lsum[mt] += (p[0] + p[1]) + (p[2] + p[3]);
                u32x2 w;
                w.x = pack2bf(p[0], p[1]);
                w.y = pack2bf(p[2], p[3]);
                *(u32x2*)&QP[prow + nt * 16 + quad * 4] = w;
            }
        }
        asm volatile("s_waitcnt lgkmcnt(0)" ::: "memory");

#pragma unroll
        for (int kt = 0; kt < 2; kt++) {
            const unsigned short* VTk = kt ? VT1 : VT0;
            short8 ap[2];
#pragma unroll
            for (int mt = 0; mt < 2; mt++)
                ap[mt] = *(const short8*)&QP[(wm + mt * 16 + l15) * 72 + kt * 32 + quad * 8];
#pragma unroll
            for (int ct = 0; ct < 4; ct++) {
                short8 bvf = *(const short8*)&VTk[(ct * 16 + l15) * 32 + quad * 8];
#pragma unroll
                for (int mt = 0; mt < 2; mt++) oacc[mt][ct] = MFMA16(ap[mt], bvf, oacc[mt][ct]);
            }
        }
    }

    float inv[2][4];
#pragma unroll
    for (int mt = 0; mt < 2; mt++) {
        float v = lsum[mt];
        v += __shfl_xor(v, 16, 64);
        v += __shfl_xor(v, 32, 64);
        float r = 1.0f / v;
#pragma unroll
        for (int i = 0; i < 4; i++) inv[mt][i] = __shfl(r, quad * 4 + i, 16);
    }

    const int bb = bh >> 4, h = bh & 15;
#pragma unroll
    for (int mt = 0; mt < 2; mt++)
#pragma unroll
        for (int i = 0; i < 4; i++) {
            int m = q0 + wm + mt * 16 + quad * 4 + i;
            size_t rowbase = ((size_t)(bb * 2048 + m)) * 1024 + h * 64;
#pragma unroll
            for (int ct = 0; ct < 4; ct++)
                O[rowbase + ct * 16 + l15] = f2bf(oacc[mt][ct][i] * inv[mt][i]);
        }
}

extern "C" void kernel_launch(void* const* d_in, const int* in_sizes, int n_in, void* d_out,
                              int out_size, void* d_ws, size_t ws_size, hipStream_t stream) {
    (void)in_sizes; (void)n_in; (void)out_size;
    const float* x = (const float*)d_in[0];    // [4,2048,1024] f32
    const float* v_w = (const float*)d_in[1];  // [1024,1024] (out,in)
    const float* v_b = (const float*)d_in[2];  // [1024]
    const float* o_w = (const float*)d_in[3];  // [1024,1024]
    const float* o_b = (const float*)d_in[4];  // [1024]
    float* out = (float*)d_out;                // [8192,1024] f32 = 32 MB

    unsigned short* Vbuf = (unsigned short*)d_out;       // V bf16 (16 MB)
    unsigned short* Vtbuf = Vbuf + (size_t)8192 * 1024;  // Vt bf16 (16 MB)
    unsigned short* Obuf = (unsigned short*)d_ws;        // 16.78 MB (proven OK)

    const size_t need =
        ((size_t)8192 * 1024 /*Obuf*/ + (size_t)8192 * 1024 /*x*/ + 2 * (size_t)1024 * 1024) * 2;
    if (ws_size >= need) {
        unsigned short* xbf = Obuf + (size_t)8192 * 1024;
        unsigned short* wv = xbf + (size_t)8192 * 1024;
        unsigned short* wo = wv + (size_t)1024 * 1024;
        cvt_kernel<<<4096, 256, 0, stream>>>(x, xbf, 1048576);
        cvt_kernel<<<512, 256, 0, stream>>>(v_w, wv, 131072);
        cvt_kernel<<<512, 256, 0, stream>>>(o_w, wo, 131072);
        gemm_dma_kernel<0><<<dim3(64, 8), 256, 0, stream>>>(xbf, wv, v_b, Vbuf, 8192, 1024, 1024);
        transpose_kernel<<<dim3(32, 64), 256, 0, stream>>>(Vbuf, Vtbuf);
        attn_kernel<<<dim3(16, 64), 256, 0, stream>>>(Vbuf, Vtbuf, Obuf);
        gemm_dma_kernel<1><<<dim3(64, 8), 256, 0, stream>>>(Obuf, wo, o_b, out, 8192, 1024, 1024);
    } else {
        gemm_bias_kernel<true, true, 0>
            <<<dim3(64, 8), 256, 0, stream>>>(x, v_w, v_b, Vbuf, 8192, 1024, 1024);
        transpose_kernel<<<dim3(32, 64), 256, 0, stream>>>(Vbuf, Vtbuf);
        attn_kernel<<<dim3(16, 64), 256, 0, stream>>>(Vbuf, Vtbuf, Obuf);
        gemm_bias_kernel<false, true, 1>
            <<<dim3(64, 8), 256, 0, stream>>>(Obuf, o_w, o_b, out, 8192, 1024, 1024);
    }
}